// Round 2
// baseline (5028.450 us; speedup 1.0000x reference)
//
#include <hip/hip_runtime.h>

#define N_USERS 50000
#define N_ENT   150000
#define N_NODES 200000
#define NE      2000000
#define BATCH   8192
#define STRIDE  64      // ego/side leading dim (padded to 64 for all layers)
#define EMB_STRIDE 112  // normalized embs: 64 + 32 + 16

// ---------------------------------------------------------------------------
// ego = concat(user_embed, entity_embed), float4-vectorized copy
// ---------------------------------------------------------------------------
__global__ __launch_bounds__(256) void init_ego(const float* __restrict__ ue,
                                                const float* __restrict__ ee,
                                                float* __restrict__ ego) {
    int i = blockIdx.x * 256 + threadIdx.x;              // float4 index
    const int total = N_NODES * STRIDE / 4;
    if (i >= total) return;
    const int uelems = N_USERS * STRIDE / 4;
    float4 v = (i < uelems) ? ((const float4*)ue)[i]
                            : ((const float4*)ee)[i - uelems];
    ((float4*)ego)[i] = v;
}

// ---------------------------------------------------------------------------
// side[rows[e]] += edge_vals[e] * ego[cols[e]]   (C = din/4 float4 chunks)
// C consecutive lanes handle one edge -> coalesced gather
// ---------------------------------------------------------------------------
template <int C>
__global__ __launch_bounds__(256) void scatter_edges(const int* __restrict__ rows,
                                                     const int* __restrict__ cols,
                                                     const float* __restrict__ vals,
                                                     const float* __restrict__ ego,
                                                     float* __restrict__ side) {
    int tid = blockIdx.x * 256 + threadIdx.x;
    if (tid >= NE * C) return;
    int e = tid / C;
    int c = tid % C;
    int r  = rows[e];
    int cl = cols[e];
    float v = vals[e];
    float4 x = ((const float4*)(ego + (size_t)cl * STRIDE))[c];
    float* dst = side + (size_t)r * STRIDE + c * 4;
    unsafeAtomicAdd(dst + 0, v * x.x);
    unsafeAtomicAdd(dst + 1, v * x.y);
    unsafeAtomicAdd(dst + 2, v * x.z);
    unsafeAtomicAdd(dst + 3, v * x.w);
}

// ---------------------------------------------------------------------------
// Per-row: h = ego+side; p = ego*side
//   new = lrelu(h@Wg + bg) + lrelu(p@Wb + bb)
//   ego <- new ; emb[:, EMB_OFF:EMB_OFF+DOUT] <- new / max(||new||, 1e-12)
// One sub-group of DOUT lanes per row; row data broadcast via __shfl.
// NOTE: __shfl returns the SOURCE lane's value of the variable, so when row
// data spans 2 registers we must shuffle BOTH and select afterwards using the
// consumer's slot index (selecting before the shuffle uses the source lane's
// own sub -> wrong rows mixed in; that was the round-1 absmax=0.22 bug).
// ---------------------------------------------------------------------------
template <int DIN, int DOUT, int EMB_OFF>
__global__ __launch_bounds__(256) void transform(float* __restrict__ ego,
                                                 const float* __restrict__ side,
                                                 const float* __restrict__ Wg,
                                                 const float* __restrict__ bg,
                                                 const float* __restrict__ Wb,
                                                 const float* __restrict__ bb,
                                                 float* __restrict__ emb) {
    __shared__ float sWg[DIN * DOUT];
    __shared__ float sWb[DIN * DOUT];
    __shared__ float sbg[DOUT];
    __shared__ float sbb[DOUT];
    for (int i = threadIdx.x; i < DIN * DOUT; i += 256) {
        sWg[i] = Wg[i];
        sWb[i] = Wb[i];
    }
    if (threadIdx.x < DOUT) {
        sbg[threadIdx.x] = bg[threadIdx.x];
        sbb[threadIdx.x] = bb[threadIdx.x];
    }
    __syncthreads();

    constexpr int R    = 64 / DOUT;   // rows per wave
    constexpr int RPB  = 4 * R;       // rows per block (4 waves)
    constexpr int NSLOT = R * DIN;    // 64 or 128 values per wave
    constexpr int REGS = (NSLOT + 63) / 64;

    const int lane = threadIdx.x & 63;
    const int wave = threadIdx.x >> 6;
    const int sub  = lane / DOUT;     // which row within the wave
    const int j    = lane % DOUT;     // output column

    const int ngroups = (N_NODES + RPB - 1) / RPB;
    for (int g = blockIdx.x; g < ngroups; g += gridDim.x) {
        const int wrow0 = g * RPB + wave * R;

        float hreg[REGS], preg[REGS];
#pragma unroll
        for (int t = 0; t < REGS; t++) {
            int slot = lane + t * 64;
            float e = 0.f, s = 0.f;
            if (slot < NSLOT) {
                int r = slot / DIN, k = slot % DIN;
                int row = wrow0 + r;
                if (row < N_NODES) {
                    e = ego[(size_t)row * STRIDE + k];
                    s = side[(size_t)row * STRIDE + k];
                }
            }
            hreg[t] = e + s;
            preg[t] = e * s;
        }

        float ag = sbg[j];
        float ab = sbb[j];
#pragma unroll
        for (int k = 0; k < DIN; k++) {
            const int slot = sub * DIN + k;   // where h[row=sub][k] lives
            const int src  = slot & 63;       // ...in this lane
            const int rsel = slot >> 6;       // ...in this register
            float hk, pk;
            if (REGS > 1) {
                float h0 = __shfl(hreg[0], src);
                float p0 = __shfl(preg[0], src);
                float h1 = __shfl(hreg[1], src);
                float p1 = __shfl(preg[1], src);
                hk = rsel ? h1 : h0;
                pk = rsel ? p1 : p0;
            } else {
                hk = __shfl(hreg[0], src);
                pk = __shfl(preg[0], src);
            }
            ag = fmaf(hk, sWg[k * DOUT + j], ag);
            ab = fmaf(pk, sWb[k * DOUT + j], ab);
        }
        ag = ag > 0.f ? ag : 0.01f * ag;   // leaky_relu, slope 0.01
        ab = ab > 0.f ? ab : 0.01f * ab;
        float nv = ag + ab;

        float ss = nv * nv;                // l2 norm over the DOUT lanes of this row
#pragma unroll
        for (int off = DOUT / 2; off > 0; off >>= 1) ss += __shfl_xor(ss, off);
        float inv = 1.0f / fmaxf(sqrtf(ss), 1e-12f);

        int row = wrow0 + sub;
        if (row < N_NODES) {
            ego[(size_t)row * STRIDE + j] = nv;
            emb[(size_t)row * EMB_STRIDE + EMB_OFF + j] = nv * inv;
        }
    }
}

// ---------------------------------------------------------------------------
// Final scoring: one wave per batch element, 176-dim dot for pos and neg.
// dim d<64 -> raw layer-0 embedding (from inputs); d>=64 -> normalized embs.
// ---------------------------------------------------------------------------
__device__ __forceinline__ float get_dim(int node, int d,
                                         const float* __restrict__ ue,
                                         const float* __restrict__ ee,
                                         const float* __restrict__ emb) {
    if (d < 64) {
        return (node < N_USERS) ? ue[(size_t)node * 64 + d]
                                : ee[(size_t)(node - N_USERS) * 64 + d];
    }
    return emb[(size_t)node * EMB_STRIDE + (d - 64)];
}

__global__ __launch_bounds__(256) void score_kernel(const int* __restrict__ users,
                                                    const int* __restrict__ pos,
                                                    const int* __restrict__ neg,
                                                    const float* __restrict__ ue,
                                                    const float* __restrict__ ee,
                                                    const float* __restrict__ emb,
                                                    float* __restrict__ out) {
    int gid  = blockIdx.x * 256 + threadIdx.x;
    int idx  = gid >> 6;
    int lane = gid & 63;
    if (idx >= BATCH) return;
    int u     = users[idx];
    int pnode = N_USERS + pos[idx];
    int nnode = N_USERS + neg[idx];
    float ap = 0.f, an = 0.f;
#pragma unroll
    for (int t = 0; t < 3; t++) {
        int d = lane + t * 64;
        if (d < 176) {
            float uu = get_dim(u, d, ue, ee, emb);
            ap += uu * get_dim(pnode, d, ue, ee, emb);
            an += uu * get_dim(nnode, d, ue, ee, emb);
        }
    }
#pragma unroll
    for (int off = 32; off > 0; off >>= 1) {
        ap += __shfl_xor(ap, off);
        an += __shfl_xor(an, off);
    }
    if (lane == 0) {
        out[2 * idx + 0] = ap;
        out[2 * idx + 1] = an;
    }
}

// ---------------------------------------------------------------------------
extern "C" void kernel_launch(void* const* d_in, const int* in_sizes, int n_in,
                              void* d_out, int out_size, void* d_ws, size_t ws_size,
                              hipStream_t stream) {
    const int*   users = (const int*)d_in[0];
    const int*   pos   = (const int*)d_in[1];
    const int*   neg   = (const int*)d_in[2];
    const int*   rows  = (const int*)d_in[3];
    const int*   cols  = (const int*)d_in[4];
    const float* vals  = (const float*)d_in[5];
    const float* ue    = (const float*)d_in[6];
    const float* ee    = (const float*)d_in[7];
    const float* Wg0 = (const float*)d_in[8],  *bg0 = (const float*)d_in[9];
    const float* Wb0 = (const float*)d_in[10], *bb0 = (const float*)d_in[11];
    const float* Wg1 = (const float*)d_in[12], *bg1 = (const float*)d_in[13];
    const float* Wb1 = (const float*)d_in[14], *bb1 = (const float*)d_in[15];
    const float* Wg2 = (const float*)d_in[16], *bg2 = (const float*)d_in[17];
    const float* Wb2 = (const float*)d_in[18], *bb2 = (const float*)d_in[19];

    float* ego  = (float*)d_ws;                       // N x 64
    float* side = ego  + (size_t)N_NODES * STRIDE;    // N x 64
    float* emb  = side + (size_t)N_NODES * STRIDE;    // N x 112 (normalized layers)

    const size_t side_bytes = (size_t)N_NODES * STRIDE * sizeof(float);

    init_ego<<<(N_NODES * STRIDE / 4 + 255) / 256, 256, 0, stream>>>(ue, ee, ego);

    // ---- layer 0: din=64, dout=64 ----
    hipMemsetAsync(side, 0, side_bytes, stream);
    scatter_edges<16><<<(NE * 16 + 255) / 256, 256, 0, stream>>>(rows, cols, vals, ego, side);
    transform<64, 64, 0><<<2048, 256, 0, stream>>>(ego, side, Wg0, bg0, Wb0, bb0, emb);

    // ---- layer 1: din=64, dout=32 ----
    hipMemsetAsync(side, 0, side_bytes, stream);
    scatter_edges<16><<<(NE * 16 + 255) / 256, 256, 0, stream>>>(rows, cols, vals, ego, side);
    transform<64, 32, 64><<<2048, 256, 0, stream>>>(ego, side, Wg1, bg1, Wb1, bb1, emb);

    // ---- layer 2: din=32, dout=16 ----
    hipMemsetAsync(side, 0, side_bytes, stream);
    scatter_edges<8><<<(NE * 8 + 255) / 256, 256, 0, stream>>>(rows, cols, vals, ego, side);
    transform<32, 16, 96><<<2048, 256, 0, stream>>>(ego, side, Wg2, bg2, Wb2, bb2, emb);

    // ---- scoring ----
    score_kernel<<<(BATCH * 64) / 256, 256, 0, stream>>>(users, pos, neg, ue, ee, emb,
                                                         (float*)d_out);
}

// Round 3
// 1570.614 us; speedup vs baseline: 3.2016x; 3.2016x over previous
//
#include <hip/hip_runtime.h>

#define N_USERS 50000
#define N_ENT   150000
#define N_NODES 200000
#define NE      2000000
#define BATCH   8192
#define EMB_STRIDE 112  // normalized outputs: 64 (L0) + 32 (L1) + 16 (L2)
#define NB 782          // ceil(N_NODES / 256)

// ===========================================================================
// CSR build: histogram -> exclusive scan (3 kernels) -> atomic-cursor fill.
// After fill, rs[r] == row_end; row_start = rs[r] - deg[r].
// ===========================================================================
__global__ __launch_bounds__(256) void hist_kernel(const int* __restrict__ rows,
                                                   int* __restrict__ deg) {
    int e = blockIdx.x * 256 + threadIdx.x;
    if (e < NE) atomicAdd(&deg[rows[e]], 1);
}

__global__ __launch_bounds__(256) void scan1(const int* __restrict__ deg,
                                             int* __restrict__ rs,
                                             int* __restrict__ blk) {
    __shared__ int buf[256];
    int i = blockIdx.x * 256 + threadIdx.x;
    int v = (i < N_NODES) ? deg[i] : 0;
    buf[threadIdx.x] = v;
    __syncthreads();
    for (int off = 1; off < 256; off <<= 1) {            // Hillis-Steele inclusive
        int x = (threadIdx.x >= off) ? buf[threadIdx.x - off] : 0;
        __syncthreads();
        buf[threadIdx.x] += x;
        __syncthreads();
    }
    if (i < N_NODES) rs[i] = buf[threadIdx.x] - v;       // exclusive
    if (threadIdx.x == 255) blk[blockIdx.x] = buf[255];  // block total
}

__global__ __launch_bounds__(1024) void scan2(int* __restrict__ blk) {
    __shared__ int buf[1024];
    int t = threadIdx.x;
    int v = (t < NB) ? blk[t] : 0;
    buf[t] = v;
    __syncthreads();
    for (int off = 1; off < 1024; off <<= 1) {
        int x = (t >= off) ? buf[t - off] : 0;
        __syncthreads();
        buf[t] += x;
        __syncthreads();
    }
    if (t < NB) blk[t] = buf[t] - v;                     // exclusive block offsets
}

__global__ __launch_bounds__(256) void scan3(int* __restrict__ rs,
                                             const int* __restrict__ blk) {
    int i = blockIdx.x * 256 + threadIdx.x;
    if (i < N_NODES) rs[i] += blk[blockIdx.x];
}

__global__ __launch_bounds__(256) void fill_kernel(const int* __restrict__ rows,
                                                   const int* __restrict__ cols,
                                                   const float* __restrict__ vals,
                                                   int* __restrict__ rs,
                                                   int* __restrict__ ccol,
                                                   float* __restrict__ cval) {
    int e = blockIdx.x * 256 + threadIdx.x;
    if (e >= NE) return;
    int pos = atomicAdd(&rs[rows[e]], 1);
    ccol[pos] = cols[e];
    cval[pos] = vals[e];
}

// ===========================================================================
// Fused per-layer kernel: one WAVE per row, lane = dim.
//   side = sum_{edges of row} val * x[col]        (CSR gather, no atomics)
//   h = x[row]+side ; p = x[row]*side
//   nv = lrelu(h@Wg+bg) + lrelu(p@Wb+bb)
//   emb[row][OUT_OFF+j] = nv/max(||nv||,1e-12) ; norm_out[row] = ||nv||
// Input x: IN_OFF<0 -> raw ue/ee (layer 0); else denormalize emb section:
//   x[col][k] = emb[col][IN_OFF+k] * norm_in[col]   (~1 ulp vs exact, fine).
// Layer l writes only its own emb section -> no cross-layer race, no dbuf.
// ===========================================================================
template <int DIN, int DOUT, int IN_OFF, int OUT_OFF>
__global__ __launch_bounds__(256) void spmm_transform(
        const int* __restrict__ rs, const int* __restrict__ deg,
        const int* __restrict__ ccol, const float* __restrict__ cval,
        const float* __restrict__ ue, const float* __restrict__ ee,
        float* __restrict__ emb,
        const float* __restrict__ norm_in, float* __restrict__ norm_out,
        const float* __restrict__ Wg, const float* __restrict__ bg,
        const float* __restrict__ Wb, const float* __restrict__ bb) {
    __shared__ float sWg[DIN * DOUT];
    __shared__ float sWb[DIN * DOUT];
    __shared__ float sbg[DOUT];
    __shared__ float sbb[DOUT];
    for (int i = threadIdx.x; i < DIN * DOUT; i += 256) {
        sWg[i] = Wg[i];
        sWb[i] = Wb[i];
    }
    if (threadIdx.x < DOUT) {
        sbg[threadIdx.x] = bg[threadIdx.x];
        sbb[threadIdx.x] = bb[threadIdx.x];
    }
    __syncthreads();

    const int lane = threadIdx.x & 63;
    const int row  = (blockIdx.x * 256 + threadIdx.x) >> 6;
    if (row >= N_NODES) return;

    // ---- CSR gather: side[lane] for this row ----
    float acc = 0.f;
    const int end   = rs[row];
    const int start = end - deg[row];
    for (int base = start; base < end; base += 64) {
        int n = end - base;
        if (n > 64) n = 64;
        int   mycol = 0;
        float myval = 0.f;
        if (lane < n) { mycol = ccol[base + lane]; myval = cval[base + lane]; }
        for (int i = 0; i < n; i++) {
            int   col = __shfl(mycol, i);
            float v   = __shfl(myval, i);
            if (lane < DIN) {
                float x;
                if (IN_OFF < 0) {
                    x = (col < N_USERS) ? ue[(size_t)col * 64 + lane]
                                        : ee[(size_t)(col - N_USERS) * 64 + lane];
                } else {
                    x = emb[(size_t)col * EMB_STRIDE + IN_OFF + lane] * norm_in[col];
                }
                acc = fmaf(v, x, acc);
            }
        }
    }

    // ---- own ego value ----
    float e = 0.f;
    if (lane < DIN) {
        if (IN_OFF < 0) {
            e = (row < N_USERS) ? ue[(size_t)row * 64 + lane]
                                : ee[(size_t)(row - N_USERS) * 64 + lane];
        } else {
            e = emb[(size_t)row * EMB_STRIDE + IN_OFF + lane] * norm_in[row];
        }
    }
    float h = e + acc;
    float p = e * acc;

    // ---- dense transform via wave broadcast ----
    float ag = (lane < DOUT) ? sbg[lane] : 0.f;
    float ab = (lane < DOUT) ? sbb[lane] : 0.f;
#pragma unroll
    for (int k = 0; k < DIN; k++) {
        float hk = __shfl(h, k);
        float pk = __shfl(p, k);
        if (lane < DOUT) {
            ag = fmaf(hk, sWg[k * DOUT + lane], ag);
            ab = fmaf(pk, sWb[k * DOUT + lane], ab);
        }
    }
    ag = ag > 0.f ? ag : 0.01f * ag;   // leaky_relu slope 0.01
    ab = ab > 0.f ? ab : 0.01f * ab;
    float nv = (lane < DOUT) ? (ag + ab) : 0.f;

    float ss = nv * nv;
#pragma unroll
    for (int off = 32; off > 0; off >>= 1) ss += __shfl_xor(ss, off);
    float nrm = fmaxf(sqrtf(ss), 1e-12f);
    float inv = 1.0f / nrm;

    if (lane < DOUT) emb[(size_t)row * EMB_STRIDE + OUT_OFF + lane] = nv * inv;
    if (lane == 0 && norm_out) norm_out[row] = nrm;
}

// ===========================================================================
// Scoring: one wave per batch element; dims 0-63 raw ue/ee, 64-175 from emb.
// ===========================================================================
__device__ __forceinline__ float get_dim(int node, int d,
                                         const float* __restrict__ ue,
                                         const float* __restrict__ ee,
                                         const float* __restrict__ emb) {
    if (d < 64) {
        return (node < N_USERS) ? ue[(size_t)node * 64 + d]
                                : ee[(size_t)(node - N_USERS) * 64 + d];
    }
    return emb[(size_t)node * EMB_STRIDE + (d - 64)];
}

__global__ __launch_bounds__(256) void score_kernel(const int* __restrict__ users,
                                                    const int* __restrict__ pos,
                                                    const int* __restrict__ neg,
                                                    const float* __restrict__ ue,
                                                    const float* __restrict__ ee,
                                                    const float* __restrict__ emb,
                                                    float* __restrict__ out) {
    int gid  = blockIdx.x * 256 + threadIdx.x;
    int idx  = gid >> 6;
    int lane = gid & 63;
    if (idx >= BATCH) return;
    int u     = users[idx];
    int pnode = N_USERS + pos[idx];
    int nnode = N_USERS + neg[idx];
    float ap = 0.f, an = 0.f;
#pragma unroll
    for (int t = 0; t < 3; t++) {
        int d = lane + t * 64;
        if (d < 176) {
            float uu = get_dim(u, d, ue, ee, emb);
            ap += uu * get_dim(pnode, d, ue, ee, emb);
            an += uu * get_dim(nnode, d, ue, ee, emb);
        }
    }
#pragma unroll
    for (int off = 32; off > 0; off >>= 1) {
        ap += __shfl_xor(ap, off);
        an += __shfl_xor(an, off);
    }
    if (lane == 0) {
        out[2 * idx + 0] = ap;
        out[2 * idx + 1] = an;
    }
}

// ===========================================================================
extern "C" void kernel_launch(void* const* d_in, const int* in_sizes, int n_in,
                              void* d_out, int out_size, void* d_ws, size_t ws_size,
                              hipStream_t stream) {
    const int*   users = (const int*)d_in[0];
    const int*   pos   = (const int*)d_in[1];
    const int*   neg   = (const int*)d_in[2];
    const int*   rows  = (const int*)d_in[3];
    const int*   cols  = (const int*)d_in[4];
    const float* vals  = (const float*)d_in[5];
    const float* ue    = (const float*)d_in[6];
    const float* ee    = (const float*)d_in[7];
    const float* Wg0 = (const float*)d_in[8],  *bg0 = (const float*)d_in[9];
    const float* Wb0 = (const float*)d_in[10], *bb0 = (const float*)d_in[11];
    const float* Wg1 = (const float*)d_in[12], *bg1 = (const float*)d_in[13];
    const float* Wb1 = (const float*)d_in[14], *bb1 = (const float*)d_in[15];
    const float* Wg2 = (const float*)d_in[16], *bg2 = (const float*)d_in[17];
    const float* Wb2 = (const float*)d_in[18], *bb2 = (const float*)d_in[19];

    // workspace layout (~110 MB)
    float* emb   = (float*)d_ws;                          // N x 112
    float* n0    = emb  + (size_t)N_NODES * EMB_STRIDE;   // N
    float* n1    = n0   + N_NODES;                        // N
    float* cval  = n1   + N_NODES;                        // E
    int*   ccol  = (int*)(cval + NE);                     // E
    int*   deg   = ccol + NE;                             // N
    int*   rs    = deg  + N_NODES;                        // N
    int*   blk   = rs   + N_NODES;                        // 1024

    // ---- CSR build (once, reused by all 3 layers) ----
    hipMemsetAsync(deg, 0, N_NODES * sizeof(int), stream);
    hist_kernel<<<(NE + 255) / 256, 256, 0, stream>>>(rows, deg);
    scan1<<<NB, 256, 0, stream>>>(deg, rs, blk);
    scan2<<<1, 1024, 0, stream>>>(blk);
    scan3<<<NB, 256, 0, stream>>>(rs, blk);
    fill_kernel<<<(NE + 255) / 256, 256, 0, stream>>>(rows, cols, vals, rs, ccol, cval);

    // ---- 3 fused layers: one wave per row ----
    const int grid = (N_NODES * 64) / 256;  // 50000
    spmm_transform<64, 64, -1,  0><<<grid, 256, 0, stream>>>(
        rs, deg, ccol, cval, ue, ee, emb, nullptr, n0, Wg0, bg0, Wb0, bb0);
    spmm_transform<64, 32,  0, 64><<<grid, 256, 0, stream>>>(
        rs, deg, ccol, cval, ue, ee, emb, n0, n1, Wg1, bg1, Wb1, bb1);
    spmm_transform<32, 16, 64, 96><<<grid, 256, 0, stream>>>(
        rs, deg, ccol, cval, ue, ee, emb, n1, nullptr, Wg2, bg2, Wb2, bb2);

    // ---- scoring ----
    score_kernel<<<(BATCH * 64) / 256, 256, 0, stream>>>(users, pos, neg, ue, ee, emb,
                                                         (float*)d_out);
}

// Round 4
// 1419.914 us; speedup vs baseline: 3.5414x; 1.1061x over previous
//
#include <hip/hip_runtime.h>

#define N_USERS 50000
#define N_ENT   150000
#define N_NODES 200000
#define NE      2000000
#define BATCH   8192
#define EMB_STRIDE 112  // normalized outputs: 64 (L0) + 32 (L1) + 16 (L2)
#define NB 782          // ceil(N_NODES / 256)

// ===========================================================================
// CSR build: histogram -> exclusive scan (3 kernels) -> atomic-cursor fill.
// After fill, rs[r] == row_end; row_start = rs[r] - deg[r].
// ===========================================================================
__global__ __launch_bounds__(256) void hist_kernel(const int* __restrict__ rows,
                                                   int* __restrict__ deg) {
    int e = blockIdx.x * 256 + threadIdx.x;
    if (e < NE) atomicAdd(&deg[rows[e]], 1);
}

__global__ __launch_bounds__(256) void scan1(const int* __restrict__ deg,
                                             int* __restrict__ rs,
                                             int* __restrict__ blk) {
    __shared__ int buf[256];
    int i = blockIdx.x * 256 + threadIdx.x;
    int v = (i < N_NODES) ? deg[i] : 0;
    buf[threadIdx.x] = v;
    __syncthreads();
    for (int off = 1; off < 256; off <<= 1) {            // Hillis-Steele inclusive
        int x = (threadIdx.x >= off) ? buf[threadIdx.x - off] : 0;
        __syncthreads();
        buf[threadIdx.x] += x;
        __syncthreads();
    }
    if (i < N_NODES) rs[i] = buf[threadIdx.x] - v;       // exclusive
    if (threadIdx.x == 255) blk[blockIdx.x] = buf[255];  // block total
}

__global__ __launch_bounds__(1024) void scan2(int* __restrict__ blk) {
    __shared__ int buf[1024];
    int t = threadIdx.x;
    int v = (t < NB) ? blk[t] : 0;
    buf[t] = v;
    __syncthreads();
    for (int off = 1; off < 1024; off <<= 1) {
        int x = (t >= off) ? buf[t - off] : 0;
        __syncthreads();
        buf[t] += x;
        __syncthreads();
    }
    if (t < NB) blk[t] = buf[t] - v;                     // exclusive block offsets
}

__global__ __launch_bounds__(256) void scan3(int* __restrict__ rs,
                                             const int* __restrict__ blk) {
    int i = blockIdx.x * 256 + threadIdx.x;
    if (i < N_NODES) rs[i] += blk[blockIdx.x];
}

__global__ __launch_bounds__(256) void fill_kernel(const int* __restrict__ rows,
                                                   const int* __restrict__ cols,
                                                   const float* __restrict__ vals,
                                                   int* __restrict__ rs,
                                                   int* __restrict__ ccol,
                                                   float* __restrict__ cval) {
    int e = blockIdx.x * 256 + threadIdx.x;
    if (e >= NE) return;
    int pos = atomicAdd(&rs[rows[e]], 1);
    ccol[pos] = cols[e];
    cval[pos] = vals[e];
}

// ---------------------------------------------------------------------------
template <int IN_OFF>
__device__ __forceinline__ float fetch_x(int col, int d,
                                         const float* __restrict__ ue,
                                         const float* __restrict__ ee,
                                         const float* __restrict__ emb) {
    if (IN_OFF < 0) {
        return (col < N_USERS) ? ue[(size_t)col * 64 + d]
                               : ee[(size_t)(col - N_USERS) * 64 + d];
    }
    return emb[(size_t)col * EMB_STRIDE + IN_OFF + d];
}

// ===========================================================================
// Fused per-layer kernel: one WAVE per row (DIN=64) or 2 edges/wave (DIN=32).
//   side = sum v * x[col]  (CSR gather, 4 edges-in-flight ILP, zero-padded)
//   h = x[row]+side ; p = x[row]*side
//   nv = lrelu(h@Wg+bg) + lrelu(p@Wb+bb)
//   emb[row][OUT_OFF+:DOUT] = nv/max(||nv||,1e-12) ; norm_out[row] = ||nv||
// norm_in premultiplied into edge val at batch-load time (once per edge).
// Block = 1024 so the 33 KB weight LDS is amortized over 16 waves
// (256-thread blocks capped occupancy at 16 waves/CU -> 41% measured in r3).
// ===========================================================================
template <int DIN, int DOUT, int IN_OFF, int OUT_OFF>
__global__ __launch_bounds__(1024) void spmm_transform(
        const int* __restrict__ rs, const int* __restrict__ deg,
        const int* __restrict__ ccol, const float* __restrict__ cval,
        const float* __restrict__ ue, const float* __restrict__ ee,
        float* __restrict__ emb,
        const float* __restrict__ norm_in, float* __restrict__ norm_out,
        const float* __restrict__ Wg, const float* __restrict__ bg,
        const float* __restrict__ Wb, const float* __restrict__ bb) {
    __shared__ float sWg[DIN * DOUT];
    __shared__ float sWb[DIN * DOUT];
    __shared__ float sbg[DOUT];
    __shared__ float sbb[DOUT];
    for (int i = threadIdx.x; i < DIN * DOUT; i += 1024) {
        sWg[i] = Wg[i];
        sWb[i] = Wb[i];
    }
    if (threadIdx.x < DOUT) {
        sbg[threadIdx.x] = bg[threadIdx.x];
        sbb[threadIdx.x] = bb[threadIdx.x];
    }
    __syncthreads();

    constexpr int EPG = 64 / DIN;     // edge slots per wave iteration
    const int lane = threadIdx.x & 63;
    const int g    = lane / DIN;      // edge sub-slot (0 for DIN=64)
    const int d    = lane % DIN;      // dim
    const int row  = (blockIdx.x * 1024 + threadIdx.x) >> 6;
    if (row >= N_NODES) return;

    // ---- CSR gather with 4-way ILP ----
    float acc0 = 0.f, acc1 = 0.f, acc2 = 0.f, acc3 = 0.f;
    const int end   = rs[row];
    const int start = end - deg[row];
    for (int base = start; base < end; base += 64) {
        int n = end - base;
        if (n > 64) n = 64;
        int   mycol = 0;
        float myval = 0.f;                 // 0 for pad lanes -> fma adds 0
        if (lane < n) {
            mycol = ccol[base + lane];
            myval = cval[base + lane];
            if (IN_OFF >= 0) myval *= norm_in[mycol];   // fold denorm into val
        }
        const int np = (n + 4 * EPG - 1) & ~(4 * EPG - 1);  // pad to unroll width
        for (int i = 0; i < np; i += 4 * EPG) {
            int c0 = __shfl(mycol, i + 0 * EPG + g);
            int c1 = __shfl(mycol, i + 1 * EPG + g);
            int c2 = __shfl(mycol, i + 2 * EPG + g);
            int c3 = __shfl(mycol, i + 3 * EPG + g);
            float v0 = __shfl(myval, i + 0 * EPG + g);
            float v1 = __shfl(myval, i + 1 * EPG + g);
            float v2 = __shfl(myval, i + 2 * EPG + g);
            float v3 = __shfl(myval, i + 3 * EPG + g);
            float x0 = fetch_x<IN_OFF>(c0, d, ue, ee, emb);
            float x1 = fetch_x<IN_OFF>(c1, d, ue, ee, emb);
            float x2 = fetch_x<IN_OFF>(c2, d, ue, ee, emb);
            float x3 = fetch_x<IN_OFF>(c3, d, ue, ee, emb);
            acc0 = fmaf(v0, x0, acc0);
            acc1 = fmaf(v1, x1, acc1);
            acc2 = fmaf(v2, x2, acc2);
            acc3 = fmaf(v3, x3, acc3);
        }
    }
    float acc = (acc0 + acc1) + (acc2 + acc3);
    if (DIN == 32) acc += __shfl_xor(acc, 32);   // combine the 2 edge sub-slots

    // ---- own ego value ----
    float e = 0.f;
    if (lane < DIN) {
        if (IN_OFF < 0) {
            e = (row < N_USERS) ? ue[(size_t)row * 64 + lane]
                                : ee[(size_t)(row - N_USERS) * 64 + lane];
        } else {
            e = emb[(size_t)row * EMB_STRIDE + IN_OFF + lane] * norm_in[row];
        }
    }
    float h = e + acc;
    float p = e * acc;

    // ---- dense transform via wave broadcast ----
    float ag = (lane < DOUT) ? sbg[lane] : 0.f;
    float ab = (lane < DOUT) ? sbb[lane] : 0.f;
#pragma unroll
    for (int k = 0; k < DIN; k++) {
        float hk = __shfl(h, k);
        float pk = __shfl(p, k);
        if (lane < DOUT) {
            ag = fmaf(hk, sWg[k * DOUT + lane], ag);
            ab = fmaf(pk, sWb[k * DOUT + lane], ab);
        }
    }
    ag = ag > 0.f ? ag : 0.01f * ag;   // leaky_relu slope 0.01
    ab = ab > 0.f ? ab : 0.01f * ab;
    float nv = (lane < DOUT) ? (ag + ab) : 0.f;

    float ss = nv * nv;
#pragma unroll
    for (int off = 32; off > 0; off >>= 1) ss += __shfl_xor(ss, off);
    float nrm = fmaxf(sqrtf(ss), 1e-12f);
    float inv = 1.0f / nrm;

    if (lane < DOUT) emb[(size_t)row * EMB_STRIDE + OUT_OFF + lane] = nv * inv;
    if (lane == 0 && norm_out) norm_out[row] = nrm;
}

// ===========================================================================
// Scoring: one wave per batch element; dims 0-63 raw ue/ee, 64-175 from emb.
// ===========================================================================
__device__ __forceinline__ float get_dim(int node, int d,
                                         const float* __restrict__ ue,
                                         const float* __restrict__ ee,
                                         const float* __restrict__ emb) {
    if (d < 64) {
        return (node < N_USERS) ? ue[(size_t)node * 64 + d]
                                : ee[(size_t)(node - N_USERS) * 64 + d];
    }
    return emb[(size_t)node * EMB_STRIDE + (d - 64)];
}

__global__ __launch_bounds__(256) void score_kernel(const int* __restrict__ users,
                                                    const int* __restrict__ pos,
                                                    const int* __restrict__ neg,
                                                    const float* __restrict__ ue,
                                                    const float* __restrict__ ee,
                                                    const float* __restrict__ emb,
                                                    float* __restrict__ out) {
    int gid  = blockIdx.x * 256 + threadIdx.x;
    int idx  = gid >> 6;
    int lane = gid & 63;
    if (idx >= BATCH) return;
    int u     = users[idx];
    int pnode = N_USERS + pos[idx];
    int nnode = N_USERS + neg[idx];
    float ap = 0.f, an = 0.f;
#pragma unroll
    for (int t = 0; t < 3; t++) {
        int d = lane + t * 64;
        if (d < 176) {
            float uu = get_dim(u, d, ue, ee, emb);
            ap += uu * get_dim(pnode, d, ue, ee, emb);
            an += uu * get_dim(nnode, d, ue, ee, emb);
        }
    }
#pragma unroll
    for (int off = 32; off > 0; off >>= 1) {
        ap += __shfl_xor(ap, off);
        an += __shfl_xor(an, off);
    }
    if (lane == 0) {
        out[2 * idx + 0] = ap;
        out[2 * idx + 1] = an;
    }
}

// ===========================================================================
extern "C" void kernel_launch(void* const* d_in, const int* in_sizes, int n_in,
                              void* d_out, int out_size, void* d_ws, size_t ws_size,
                              hipStream_t stream) {
    const int*   users = (const int*)d_in[0];
    const int*   pos   = (const int*)d_in[1];
    const int*   neg   = (const int*)d_in[2];
    const int*   rows  = (const int*)d_in[3];
    const int*   cols  = (const int*)d_in[4];
    const float* vals  = (const float*)d_in[5];
    const float* ue    = (const float*)d_in[6];
    const float* ee    = (const float*)d_in[7];
    const float* Wg0 = (const float*)d_in[8],  *bg0 = (const float*)d_in[9];
    const float* Wb0 = (const float*)d_in[10], *bb0 = (const float*)d_in[11];
    const float* Wg1 = (const float*)d_in[12], *bg1 = (const float*)d_in[13];
    const float* Wb1 = (const float*)d_in[14], *bb1 = (const float*)d_in[15];
    const float* Wg2 = (const float*)d_in[16], *bg2 = (const float*)d_in[17];
    const float* Wb2 = (const float*)d_in[18], *bb2 = (const float*)d_in[19];

    // workspace layout (~110 MB)
    float* emb   = (float*)d_ws;                          // N x 112
    float* n0    = emb  + (size_t)N_NODES * EMB_STRIDE;   // N
    float* n1    = n0   + N_NODES;                        // N
    float* cval  = n1   + N_NODES;                        // E
    int*   ccol  = (int*)(cval + NE);                     // E
    int*   deg   = ccol + NE;                             // N
    int*   rs    = deg  + N_NODES;                        // N
    int*   blk   = rs   + N_NODES;                        // 1024

    // ---- CSR build (once, reused by all 3 layers) ----
    hipMemsetAsync(deg, 0, N_NODES * sizeof(int), stream);
    hist_kernel<<<(NE + 255) / 256, 256, 0, stream>>>(rows, deg);
    scan1<<<NB, 256, 0, stream>>>(deg, rs, blk);
    scan2<<<1, 1024, 0, stream>>>(blk);
    scan3<<<NB, 256, 0, stream>>>(rs, blk);
    fill_kernel<<<(NE + 255) / 256, 256, 0, stream>>>(rows, cols, vals, rs, ccol, cval);

    // ---- 3 fused layers: one wave per row, block=1024 (16 rows/block) ----
    const int grid = N_NODES * 64 / 1024;  // 12500, exact
    spmm_transform<64, 64, -1,  0><<<grid, 1024, 0, stream>>>(
        rs, deg, ccol, cval, ue, ee, emb, nullptr, n0, Wg0, bg0, Wb0, bb0);
    spmm_transform<64, 32,  0, 64><<<grid, 1024, 0, stream>>>(
        rs, deg, ccol, cval, ue, ee, emb, n0, n1, Wg1, bg1, Wb1, bb1);
    spmm_transform<32, 16, 64, 96><<<grid, 1024, 0, stream>>>(
        rs, deg, ccol, cval, ue, ee, emb, n1, nullptr, Wg2, bg2, Wb2, bb2);

    // ---- scoring ----
    score_kernel<<<(BATCH * 64) / 256, 256, 0, stream>>>(users, pos, neg, ue, ee, emb,
                                                         (float*)d_out);
}